// Round 1
// baseline (347.250 us; speedup 1.0000x reference)
//
#include <hip/hip_runtime.h>
#include <math.h>

// Problem constants (fixed by setup_inputs)
#define B_   4
#define T_   1024
#define CH_  4
#define F_   481
#define K_   48
#define NCOV 16
#define TF   64   // frequency tile

// ---------------------------------------------------------------------------
// Kernel 1: one wave (64 threads) per (b,t).
//   phase 1: normalized hermitian covariance for tile (+halo) -> LDS (packed)
//   phase 2: phase-adjusted cov (adj) -> LDS, using |cov|*w/|w| (no trig)
//   phase 3: bc[k,c] += adj[f,c]*band[f,k]  (register tile: 4 c's x 3 k's)
//   epilogue: ds normalize (shfl over c-quad), c2pv projection, store real
//             output directly into d_out layout (b,k,t,p).
// ---------------------------------------------------------------------------
__global__ __launch_bounds__(64) void pv_stage1(
    const float* __restrict__ binsR, const float* __restrict__ binsI,
    const float* __restrict__ bandR, const float* __restrict__ bandI,
    const float* __restrict__ c2pR,  const float* __restrict__ c2pI,
    float* __restrict__ out)
{
    // packed cov: [d0 d1 d2 d3 | re01 im01 re02 im02 re03 im03 re12 im12
    //              re13 im13 re23 im23 | pad..]; stride 20 keeps float4 align
    __shared__ float covS[TF + 3][20];
    __shared__ float adjS[TF][32];      // 16 complex (re,im interleaved)

    const int lane = threadIdx.x;       // 0..63
    const int blk  = blockIdx.x;        // b*T + t
    const int b    = blk >> 10;
    const int t    = blk & (T_ - 1);
    const int cq   = lane & 3;          // c-quad: c in [4cq, 4cq+3]
    const int kq   = lane >> 2;         // 0..15 : k in {kq, kq+16, kq+32}

    const float* xr = binsR + (size_t)(b * T_ + t) * CH_ * F_;
    const float* xi = binsI + (size_t)(b * T_ + t) * CH_ * F_;

    float accr[12], acci[12];           // [cc*3 + r]
    #pragma unroll
    for (int q = 0; q < 12; ++q) { accr[q] = 0.f; acci[q] = 0.f; }

    const int ntiles = (F_ + TF - 1) / TF;
    for (int tile = 0; tile < ntiles; ++tile) {
        const int ts = tile * TF;
        const int te = min(F_, ts + TF);
        const int tl = te - ts;
        const int r0 = max(0, ts - 1);
        const int r1 = min(F_ - 1, te + 1);
        const int rn = r1 - r0 + 1;     // <= TF+3

        // ---- phase 1: normalized covariance ----
        for (int iq = lane; iq < rn; iq += 64) {
            const int f = r0 + iq;
            float a0r = xr[f],          a0i = xi[f];
            float a1r = xr[F_ + f],     a1i = xi[F_ + f];
            float a2r = xr[2*F_ + f],   a2i = xi[2*F_ + f];
            float a3r = xr[3*F_ + f],   a3i = xi[3*F_ + f];
            float d0 = a0r*a0r + a0i*a0i;
            float d1 = a1r*a1r + a1i*a1i;
            float d2 = a2r*a2r + a2i*a2i;
            float d3 = a3r*a3r + a3i*a3i;
            float pinv = 1.0f / fmaxf(d0 + d1 + d2 + d3, 1e-20f);
            // cov[i][j] = x_i * conj(x_j) (i<j): re = ri*rj+ii*ij, im = ii*rj-ri*ij
            float4* row4 = reinterpret_cast<float4*>(covS[iq]);
            row4[0] = make_float4(d0*pinv, d1*pinv, d2*pinv, d3*pinv);
            row4[1] = make_float4((a0r*a1r + a0i*a1i)*pinv, (a0i*a1r - a0r*a1i)*pinv,
                                  (a0r*a2r + a0i*a2i)*pinv, (a0i*a2r - a0r*a2i)*pinv);
            row4[2] = make_float4((a0r*a3r + a0i*a3i)*pinv, (a0i*a3r - a0r*a3i)*pinv,
                                  (a1r*a2r + a1i*a2i)*pinv, (a1i*a2r - a1r*a2i)*pinv);
            row4[3] = make_float4((a1r*a3r + a1i*a3i)*pinv, (a1i*a3r - a1r*a3i)*pinv,
                                  (a2r*a3r + a2i*a3i)*pinv, (a2i*a3r - a2r*a3i)*pinv);
        }
        __syncthreads();   // block == 1 wave: cheap

        // ---- phase 2: adj = |cov[f]| * w/|w|, w = conj(cov[g])*cov[g+2] ----
        for (int q = lane; q < tl * NCOV; q += 64) {
            const int fl = q >> 4, c = q & 15;
            const int i = c >> 2, j = c & 3;
            const int fg = ts + fl;
            const float* rowF = covS[fg - r0];
            if (i == j) {
                adjS[fl][2*c]   = rowF[i];
                adjS[fl][2*c+1] = 0.f;
            } else {
                const int a  = min(i, j), bb = max(i, j);
                const int off = 4 + 2 * ((a == 0) ? (bb - 1) : (a == 1) ? (bb + 1) : 5);
                float pfr = rowF[off], pfi = rowF[off + 1];
                int g = fg - 1; g = g < 0 ? 0 : (g > F_ - 3 ? F_ - 3 : g);
                const float* rowL = covS[g - r0];
                const float* rowR = covS[g + 2 - r0];
                float Lr = rowL[off], Li = rowL[off + 1];
                float Rr = rowR[off], Ri = rowR[off + 1];
                if (i > j) { pfi = -pfi; Li = -Li; Ri = -Ri; }
                float wr = Lr * Rr + Li * Ri;
                float wi = Lr * Ri - Li * Rr;
                float n2 = wr * wr + wi * wi;
                float mag = sqrtf(pfr * pfr + pfi * pfi);
                float sr, si;
                if (n2 > 0.f) { float s = mag * rsqrtf(n2); sr = wr * s; si = wi * s; }
                else          { sr = mag; si = 0.f; }   // angle(0)=0 -> phase 1
                adjS[fl][2*c]   = sr;
                adjS[fl][2*c+1] = si;
            }
        }
        __syncthreads();

        // ---- phase 3: accumulate bc over this tile ----
        auto body = [&](int fl) {
            const float4* ap = reinterpret_cast<const float4*>(&adjS[fl][8 * cq]);
            float4 A  = ap[0];            // c0: (x,y), c1: (z,w)
            float4 Bv = ap[1];            // c2, c3
            const int fb = (ts + fl) * K_ + kq;
            float br[3], bi[3];
            br[0] = bandR[fb];      bi[0] = bandI[fb];
            br[1] = bandR[fb + 16]; bi[1] = bandI[fb + 16];
            br[2] = bandR[fb + 32]; bi[2] = bandI[fb + 32];
            float ar[4] = {A.x, A.z, Bv.x, Bv.z};
            float ai[4] = {A.y, A.w, Bv.y, Bv.w};
            #pragma unroll
            for (int cc = 0; cc < 4; ++cc) {
                #pragma unroll
                for (int r = 0; r < 3; ++r) {
                    accr[cc*3+r] = fmaf(ar[cc], br[r], fmaf(-ai[cc], bi[r], accr[cc*3+r]));
                    acci[cc*3+r] = fmaf(ar[cc], bi[r], fmaf( ai[cc], br[r], acci[cc*3+r]));
                }
            }
        };
        if (tl == TF) {
            #pragma unroll 4
            for (int fl = 0; fl < TF; ++fl) body(fl);
        } else {
            for (int fl = 0; fl < tl; ++fl) body(fl);
        }
        __syncthreads();   // before next tile overwrites LDS
    }

    // ---- epilogue ----
    // ds[k] = sum over diag c (0,5,10,15) of bc.real; lane's diag is cc==cq
    float dsi[3];
    #pragma unroll
    for (int r = 0; r < 3; ++r) {
        float d = (cq == 0) ? accr[0 + r] :
                  (cq == 1) ? accr[3 + r] :
                  (cq == 2) ? accr[6 + r] : accr[9 + r];
        d += __shfl_xor(d, 1, 64);
        d += __shfl_xor(d, 2, 64);
        dsi[r] = 1.0f / fmaxf(d, 1e-20f);
    }
    #pragma unroll
    for (int cc = 0; cc < 4; ++cc)
        #pragma unroll
        for (int r = 0; r < 3; ++r) {
            accr[cc*3+r] *= dsi[r];
            acci[cc*3+r] *= dsi[r];
        }

    // z[k][p] = Re( c2pv[p,:] . bc_norm[k,:] ), partial over lane's 4 c's
    float zp[48];   // [p*3 + r]
    #pragma unroll
    for (int q = 0; q < 48; ++q) zp[q] = 0.f;
    #pragma unroll
    for (int p = 0; p < 16; ++p) {
        const float4 cr4 = *reinterpret_cast<const float4*>(c2pR + p * 16 + 4 * cq);
        const float4 ci4 = *reinterpret_cast<const float4*>(c2pI + p * 16 + 4 * cq);
        float crr[4] = {cr4.x, cr4.y, cr4.z, cr4.w};
        float cii[4] = {ci4.x, ci4.y, ci4.z, ci4.w};
        #pragma unroll
        for (int cc = 0; cc < 4; ++cc)
            #pragma unroll
            for (int r = 0; r < 3; ++r)
                zp[p*3+r] = fmaf(crr[cc], accr[cc*3+r],
                            fmaf(-cii[cc], acci[cc*3+r], zp[p*3+r]));
    }
    #pragma unroll
    for (int q = 0; q < 48; ++q) {
        zp[q] += __shfl_xor(zp[q], 1, 64);
        zp[q] += __shfl_xor(zp[q], 2, 64);
    }
    // store: out[((b*K + k)*T + t)*16 + p]; lane owns p in [4cq, 4cq+3]
    #pragma unroll
    for (int p = 0; p < 16; ++p) {
        if (cq == (p >> 2)) {
            #pragma unroll
            for (int r = 0; r < 3; ++r) {
                const int k = kq + 16 * r;
                out[(size_t)((b * K_ + k) * T_ + t) * 16 + p] = zp[p*3+r];
            }
        }
    }
}

// ---------------------------------------------------------------------------
// Kernel 2: in-place IIR over t on the real projected output.
// One block per (b,k); threads = (p in 0..15) x (chunk j in 0..15), chunk=64.
// Zero-init partial scans in registers + exact carry correction:
//   y_t = p_t + a^{s+1} * Y_chunk,   Y_j = E_{j-1}, E_m = F_m + a^64 E_{m-1}
// ---------------------------------------------------------------------------
__global__ __launch_bounds__(256) void pv_iir(float* __restrict__ out,
                                              const float* __restrict__ tau)
{
    const int p  = threadIdx.x & 15;
    const int j  = threadIdx.x >> 4;     // chunk index 0..15
    const int bk = blockIdx.x;           // b*K + k
    const int k  = bk % K_;
    const float a   = expf(-10.0f / tau[k]);
    const float oma = 1.0f - a;
    const int t0 = j * 64;
    float* base = out + (size_t)bk * T_ * 16 + p;

    float y[64];
    float cur = 0.f;
    #pragma unroll
    for (int s = 0; s < 64; ++s) {
        float x = base[(t0 + s) * 16];
        if (j == 0 && s == 0) cur = x;          // ys[0] = xs[0] exactly
        else                  cur = fmaf(a, cur, oma * x);
        y[s] = cur;
    }

    __shared__ float Fc[16][17];
    Fc[j][p] = cur;                              // chunk-final partial
    __syncthreads();

    float a64 = a;
    #pragma unroll
    for (int q = 0; q < 6; ++q) a64 *= a64;      // a^64

    float Y = 0.f;
    if (j > 0) {
        float E = Fc[0][p];                      // chunk 0 is exact
        for (int i = 1; i < j; ++i) E = fmaf(a64, E, Fc[i][p]);
        Y = E;
    }

    float pw = a;
    #pragma unroll
    for (int s = 0; s < 64; ++s) {
        base[(t0 + s) * 16] = fmaf(pw, Y, y[s]);
        pw *= a;
    }
}

extern "C" void kernel_launch(void* const* d_in, const int* in_sizes, int n_in,
                              void* d_out, int out_size, void* d_ws, size_t ws_size,
                              hipStream_t stream) {
    const float* binsR = (const float*)d_in[0];
    const float* binsI = (const float*)d_in[1];
    const float* bandR = (const float*)d_in[2];
    const float* bandI = (const float*)d_in[3];
    const float* c2pR  = (const float*)d_in[4];
    const float* c2pI  = (const float*)d_in[5];
    const float* tau   = (const float*)d_in[6];
    float* out = (float*)d_out;

    pv_stage1<<<B_ * T_, 64, 0, stream>>>(binsR, binsI, bandR, bandI, c2pR, c2pI, out);
    pv_iir<<<B_ * K_, 256, 0, stream>>>(out, tau);
}